// Round 4
// baseline (595.089 us; speedup 1.0000x reference)
//
#include <hip/hip_runtime.h>

#define NTOK 8192
#define DIM  512
#define MHID 2048
#define EHID 1024
#define NEXP 8

using half_t = _Float16;
typedef _Float16 f16x8 __attribute__((ext_vector_type(8)));
typedef float    f32x4 __attribute__((ext_vector_type(4)));

__device__ __forceinline__ float gelu_exact(float v) {
    return 0.5f * v * (1.0f + erff(v * 0.70710678118654752f));
}

__device__ __forceinline__ f16x8 f16x8_zero() {
    f16x8 v;
#pragma unroll
    for (int i = 0; i < 8; i++) v[i] = (_Float16)0.f;
    return v;
}

// all-threads-return block sum over 4 waves (256 threads)
__device__ __forceinline__ float block_sum4(float v, float* red, int tid) {
#pragma unroll
    for (int off = 32; off; off >>= 1) v += __shfl_down(v, off);
    if ((tid & 63) == 0) red[tid >> 6] = v;
    __syncthreads();
    float r = red[0] + red[1] + red[2] + red[3];
    __syncthreads();
    return r;
}

// ---------------- LN1 + fp16 hi/lo split ----------------
__global__ __launch_bounds__(256) void ln1_split_kernel(
    const float* __restrict__ x, const float* __restrict__ g, const float* __restrict__ b,
    half_t* __restrict__ xh, half_t* __restrict__ xl)
{
    const int row = blockIdx.x, tid = threadIdx.x;
    __shared__ float red[4];
    const size_t base = (size_t)row * DIM;
    float2 v = reinterpret_cast<const float2*>(x + base)[tid];
    float mean = block_sum4(v.x + v.y, red, tid) * (1.0f / DIM);
    float d0 = v.x - mean, d1 = v.y - mean;
    float var = block_sum4(d0 * d0 + d1 * d1, red, tid) * (1.0f / DIM);
    float rstd = rsqrtf(var + 1e-5f);
    int d = tid * 2;
    float y0 = d0 * rstd * g[d]     + b[d];
    float y1 = d1 * rstd * g[d + 1] + b[d + 1];
    half_t h0 = (half_t)y0, h1 = (half_t)y1;
    xh[base + d] = h0;  xh[base + d + 1] = h1;
    xl[base + d]     = (half_t)(y0 - (float)h0);
    xl[base + d + 1] = (half_t)(y1 - (float)h1);
}

// ---------------- x2 = x + h ; x3 = LN2(x2) + x2 (in place over h) ----------------
__global__ __launch_bounds__(256) void resid_ln2_kernel(
    const float* __restrict__ x, float* __restrict__ hio,
    const float* __restrict__ g, const float* __restrict__ b,
    half_t* __restrict__ x3h)
{
    const int row = blockIdx.x, tid = threadIdx.x;
    __shared__ float red[4];
    const size_t base = (size_t)row * DIM;
    float2 xv = reinterpret_cast<const float2*>(x + base)[tid];
    float2 hv = reinterpret_cast<float2*>(hio + base)[tid];
    float z0 = xv.x + hv.x, z1 = xv.y + hv.y;
    float mean = block_sum4(z0 + z1, red, tid) * (1.0f / DIM);
    float d0 = z0 - mean, d1 = z1 - mean;
    float var = block_sum4(d0 * d0 + d1 * d1, red, tid) * (1.0f / DIM);
    float rstd = rsqrtf(var + 1e-5f);
    int d = tid * 2;
    float y0 = d0 * rstd * g[d]     + b[d]     + z0;
    float y1 = d1 * rstd * g[d + 1] + b[d + 1] + z1;
    float2 o; o.x = y0; o.y = y1;
    reinterpret_cast<float2*>(hio + base)[tid] = o;
    x3h[base + d]     = (half_t)y0;
    x3h[base + d + 1] = (half_t)y1;
}

// ---------------- transpose [R][C] -> [C][R], cast to f16 (optional lo split) ----------------
__global__ void transpose_split_kernel(const float* __restrict__ in,
                                       half_t* __restrict__ oh, half_t* __restrict__ ol,
                                       int R, int C)
{
    __shared__ float t[32][33];
    const size_t mo = (size_t)blockIdx.z * (size_t)R * (size_t)C;
    const int c0 = blockIdx.x * 32, r0 = blockIdx.y * 32;
    const int tx = threadIdx.x, ty = threadIdx.y;
    for (int i = ty; i < 32; i += 8) t[i][tx] = in[mo + (size_t)(r0 + i) * C + c0 + tx];
    __syncthreads();
    for (int i = ty; i < 32; i += 8) {
        float v = t[tx][i];
        size_t o = mo + (size_t)(c0 + i) * R + r0 + tx;
        half_t h = (half_t)v;
        oh[o] = h;
        if (ol) ol[o] = (half_t)(v - (float)h);
    }
}

// ---------------- split-3 f16 MFMA GEMM: C = (Ah+Al)(Bh+Bl)^T approx ----------------
// A: [M][K] f16 hi/lo.  B: [Nc][K] f16 hi/lo (pre-transposed weights).
// EPI==1: gelu(acc+bias) -> split f16 hi/lo outs.  EPI==0: acc+bias -> f32 out.
template <int EPI>
__global__ __launch_bounds__(256) void gemm3_kernel(
    const half_t* __restrict__ A0, const half_t* __restrict__ A1,
    const half_t* __restrict__ B0, const half_t* __restrict__ B1,
    const float* __restrict__ bias,
    float* __restrict__ Cf, half_t* __restrict__ Ch, half_t* __restrict__ Cl,
    int M, int Nc, int K)
{
    __shared__ half_t As[128][40];
    __shared__ half_t Bs[128][40];
    const int m0 = blockIdx.x * 128, n0 = blockIdx.y * 128;
    const int tid = threadIdx.x;
    const int lane = tid & 63, wid = tid >> 6;
    const int wr = wid >> 1, wc = wid & 1;
    f32x4 acc[4][4];
#pragma unroll
    for (int i = 0; i < 4; i++)
#pragma unroll
        for (int j = 0; j < 4; j++)
#pragma unroll
            for (int q = 0; q < 4; q++) acc[i][j][q] = 0.f;

    const int sm = tid >> 1, sk = (tid & 1) * 16;
    const size_t aoff = (size_t)(m0 + sm) * K + sk;
    const size_t boff = (size_t)(n0 + sm) * K + sk;
    const int kk = (lane >> 4) * 8;
    const int fr = lane & 15;

#pragma unroll 1
    for (int term = 0; term < 3; ++term) {
        const half_t* Ap = (term == 1 ? A1 : A0) + aoff;
        const half_t* Bp = (term == 2 ? B1 : B0) + boff;
#pragma unroll 1
        for (int k0 = 0; k0 < K; k0 += 32) {
            __syncthreads();
            *(f16x8*)&As[sm][sk]     = *(const f16x8*)(Ap + k0);
            *(f16x8*)&As[sm][sk + 8] = *(const f16x8*)(Ap + k0 + 8);
            *(f16x8*)&Bs[sm][sk]     = *(const f16x8*)(Bp + k0);
            *(f16x8*)&Bs[sm][sk + 8] = *(const f16x8*)(Bp + k0 + 8);
            __syncthreads();
            f16x8 af[4], bf[4];
#pragma unroll
            for (int i = 0; i < 4; i++) af[i] = *(const f16x8*)&As[wr * 64 + i * 16 + fr][kk];
#pragma unroll
            for (int i = 0; i < 4; i++) bf[i] = *(const f16x8*)&Bs[wc * 64 + i * 16 + fr][kk];
#pragma unroll
            for (int i = 0; i < 4; i++)
#pragma unroll
                for (int j = 0; j < 4; j++)
                    acc[i][j] = __builtin_amdgcn_mfma_f32_16x16x32_f16(af[i], bf[j], acc[i][j], 0, 0, 0);
        }
    }

    const int rl = (lane >> 4) * 4, cl = lane & 15;
#pragma unroll
    for (int i = 0; i < 4; i++) {
#pragma unroll
        for (int j = 0; j < 4; j++) {
            int cc = n0 + wc * 64 + j * 16 + cl;
            float bv = bias[cc];
#pragma unroll
            for (int q = 0; q < 4; q++) {
                int rr = m0 + wr * 64 + i * 16 + rl + q;
                float v = acc[i][j][q] + bv;
                size_t o = (size_t)rr * Nc + cc;
                if (EPI == 1) {
                    float ge = gelu_exact(v);
                    half_t h = (half_t)ge;
                    Ch[o] = h;
                    Cl[o] = (half_t)(ge - (float)h);
                } else {
                    Cf[o] = v;
                }
            }
        }
    }
}

// ---------------- router: logits, softmax, top2, gates, expert lists ----------------
__global__ __launch_bounds__(256) void router_kernel(
    const float* __restrict__ x3, const float* __restrict__ wrm,
    int* __restrict__ cnt, int* __restrict__ aid, float* __restrict__ gate)
{
    __shared__ float wl[NEXP][DIM];
    const int tid = threadIdx.x;
    for (int i = tid; i < NEXP * DIM / 4; i += 256)
        reinterpret_cast<float4*>(&wl[0][0])[i] = reinterpret_cast<const float4*>(wrm)[i];
    __syncthreads();
    const int w = tid >> 6, lane = tid & 63;
    const int token = blockIdx.x * 4 + w;
    const float* xr = x3 + (size_t)token * DIM;
    float a[NEXP];
#pragma unroll
    for (int e = 0; e < NEXP; e++) a[e] = 0.f;
    for (int d = lane; d < DIM; d += 64) {
        float xv = xr[d];
#pragma unroll
        for (int e = 0; e < NEXP; e++) a[e] += xv * wl[e][d];
    }
#pragma unroll
    for (int e = 0; e < NEXP; e++)
#pragma unroll
        for (int off = 32; off; off >>= 1) a[e] += __shfl_xor(a[e], off);
    if (lane == 0) {
        float m = a[0];
#pragma unroll
        for (int e = 1; e < NEXP; e++) m = fmaxf(m, a[e]);
        float p[NEXP], s = 0.f;
#pragma unroll
        for (int e = 0; e < NEXP; e++) { p[e] = expf(a[e] - m); s += p[e]; }
        float inv = 1.f / s;
#pragma unroll
        for (int e = 0; e < NEXP; e++) p[e] *= inv;
        int i1 = 0; float v1 = p[0];
#pragma unroll
        for (int e = 1; e < NEXP; e++) if (p[e] > v1) { v1 = p[e]; i1 = e; }
        int i2 = -1; float v2 = -1.f;
#pragma unroll
        for (int e = 0; e < NEXP; e++) if (e != i1 && p[e] > v2) { v2 = p[e]; i2 = e; }
        float den = v1 + v2;
        int s1 = atomicAdd(&cnt[i1], 1);
        int s2 = atomicAdd(&cnt[i2], 1);
        aid[i1 * NTOK + s1] = token * 2;
        aid[i2 * NTOK + s2] = token * 2 + 1;
        gate[token * 2]     = v1 / den;
        gate[token * 2 + 1] = v2 / den;
    }
}

// ---------------- expert GEMM1: He[a] = gelu(x3[tok] @ ew1[e] + eb1[e]) ----------------
__global__ __launch_bounds__(256) void egemm1_kernel(
    const half_t* __restrict__ X,   // [NTOK][DIM]
    const half_t* __restrict__ W,   // [E][EHID][DIM]  (transposed)
    const float* __restrict__ eb1,  // [E][EHID]
    const int* __restrict__ cnt, const int* __restrict__ aid,
    half_t* __restrict__ He)        // [2*NTOK][EHID]
{
    const int bid = blockIdx.x;
    const int e = bid >> 9, rem = bid & 511;
    const int mt = rem >> 3, nt = rem & 7;
    const int ne = cnt[e];
    if (mt * 128 >= ne) return;
    __shared__ half_t As[128][40];
    __shared__ half_t Bs[128][40];
    __shared__ int rowmap[128];
    const int tid = threadIdx.x;
    if (tid < 128) {
        int slot = mt * 128 + tid;
        rowmap[tid] = (slot < ne) ? aid[e * NTOK + slot] : -1;
    }
    __syncthreads();
    const int lane = tid & 63, wid = tid >> 6;
    const int wr = wid >> 1, wc = wid & 1;
    const int sm = tid >> 1, sk = (tid & 1) * 16;
    const int arow = rowmap[sm];
    const half_t* Ap = (arow >= 0) ? X + (size_t)(arow >> 1) * DIM + sk : (const half_t*)0;
    const half_t* Bp = W + (size_t)e * EHID * DIM + (size_t)(nt * 128 + sm) * DIM + sk;
    f32x4 acc[4][4];
#pragma unroll
    for (int i = 0; i < 4; i++)
#pragma unroll
        for (int j = 0; j < 4; j++)
#pragma unroll
            for (int q = 0; q < 4; q++) acc[i][j][q] = 0.f;
    const int kk = (lane >> 4) * 8, fr = lane & 15;
    const f16x8 zz = f16x8_zero();
#pragma unroll 1
    for (int k0 = 0; k0 < DIM; k0 += 32) {
        __syncthreads();
        if (Ap) {
            *(f16x8*)&As[sm][sk]     = *(const f16x8*)(Ap + k0);
            *(f16x8*)&As[sm][sk + 8] = *(const f16x8*)(Ap + k0 + 8);
        } else {
            *(f16x8*)&As[sm][sk]     = zz;
            *(f16x8*)&As[sm][sk + 8] = zz;
        }
        *(f16x8*)&Bs[sm][sk]     = *(const f16x8*)(Bp + k0);
        *(f16x8*)&Bs[sm][sk + 8] = *(const f16x8*)(Bp + k0 + 8);
        __syncthreads();
        f16x8 af[4], bf[4];
#pragma unroll
        for (int i = 0; i < 4; i++) af[i] = *(const f16x8*)&As[wr * 64 + i * 16 + fr][kk];
#pragma unroll
        for (int i = 0; i < 4; i++) bf[i] = *(const f16x8*)&Bs[wc * 64 + i * 16 + fr][kk];
#pragma unroll
        for (int i = 0; i < 4; i++)
#pragma unroll
            for (int j = 0; j < 4; j++)
                acc[i][j] = __builtin_amdgcn_mfma_f32_16x16x32_f16(af[i], bf[j], acc[i][j], 0, 0, 0);
    }
    const int rl = (lane >> 4) * 4, cl = lane & 15;
#pragma unroll
    for (int i = 0; i < 4; i++)
#pragma unroll
        for (int q = 0; q < 4; q++) {
            int r = wr * 64 + i * 16 + rl + q;
            int a = rowmap[r];
            if (a >= 0) {
#pragma unroll
                for (int j = 0; j < 4; j++) {
                    int cc = nt * 128 + wc * 64 + j * 16 + cl;
                    float v = acc[i][j][q] + eb1[e * EHID + cc];
                    He[(size_t)a * EHID + cc] = (half_t)gelu_exact(v);
                }
            }
        }
}

// ---------------- expert GEMM2: Ye[a] = (He[a] @ ew2[e] + eb2[e]) * gate[a] ----------------
__global__ __launch_bounds__(256) void egemm2_kernel(
    const half_t* __restrict__ Hin,  // [2*NTOK][EHID]
    const half_t* __restrict__ W,    // [E][DIM][EHID]  (transposed)
    const float* __restrict__ eb2,   // [E][DIM]
    const int* __restrict__ cnt, const int* __restrict__ aid,
    const float* __restrict__ gate,
    float* __restrict__ Ye)          // [2*NTOK][DIM]
{
    const int bid = blockIdx.x;
    const int e = bid >> 8, rem = bid & 255;
    const int mt = rem >> 2, nt = rem & 3;
    const int ne = cnt[e];
    if (mt * 128 >= ne) return;
    __shared__ half_t As[128][40];
    __shared__ half_t Bs[128][40];
    __shared__ int rowmap[128];
    const int tid = threadIdx.x;
    if (tid < 128) {
        int slot = mt * 128 + tid;
        rowmap[tid] = (slot < ne) ? aid[e * NTOK + slot] : -1;
    }
    __syncthreads();
    const int lane = tid & 63, wid = tid >> 6;
    const int wr = wid >> 1, wc = wid & 1;
    const int sm = tid >> 1, sk = (tid & 1) * 16;
    const int arow = rowmap[sm];
    const half_t* Ap = (arow >= 0) ? Hin + (size_t)arow * EHID + sk : (const half_t*)0;
    const half_t* Bp = W + (size_t)e * DIM * EHID + (size_t)(nt * 128 + sm) * EHID + sk;
    f32x4 acc[4][4];
#pragma unroll
    for (int i = 0; i < 4; i++)
#pragma unroll
        for (int j = 0; j < 4; j++)
#pragma unroll
            for (int q = 0; q < 4; q++) acc[i][j][q] = 0.f;
    const int kk = (lane >> 4) * 8, fr = lane & 15;
    const f16x8 zz = f16x8_zero();
#pragma unroll 1
    for (int k0 = 0; k0 < EHID; k0 += 32) {
        __syncthreads();
        if (Ap) {
            *(f16x8*)&As[sm][sk]     = *(const f16x8*)(Ap + k0);
            *(f16x8*)&As[sm][sk + 8] = *(const f16x8*)(Ap + k0 + 8);
        } else {
            *(f16x8*)&As[sm][sk]     = zz;
            *(f16x8*)&As[sm][sk + 8] = zz;
        }
        *(f16x8*)&Bs[sm][sk]     = *(const f16x8*)(Bp + k0);
        *(f16x8*)&Bs[sm][sk + 8] = *(const f16x8*)(Bp + k0 + 8);
        __syncthreads();
        f16x8 af[4], bf[4];
#pragma unroll
        for (int i = 0; i < 4; i++) af[i] = *(const f16x8*)&As[wr * 64 + i * 16 + fr][kk];
#pragma unroll
        for (int i = 0; i < 4; i++) bf[i] = *(const f16x8*)&Bs[wc * 64 + i * 16 + fr][kk];
#pragma unroll
        for (int i = 0; i < 4; i++)
#pragma unroll
            for (int j = 0; j < 4; j++)
                acc[i][j] = __builtin_amdgcn_mfma_f32_16x16x32_f16(af[i], bf[j], acc[i][j], 0, 0, 0);
    }
    const int rl = (lane >> 4) * 4, cl = lane & 15;
#pragma unroll
    for (int i = 0; i < 4; i++)
#pragma unroll
        for (int q = 0; q < 4; q++) {
            int r = wr * 64 + i * 16 + rl + q;
            int a = rowmap[r];
            if (a >= 0) {
                float gv = gate[a];
#pragma unroll
                for (int j = 0; j < 4; j++) {
                    int cc = nt * 128 + wc * 64 + j * 16 + cl;
                    float v = (acc[i][j][q] + eb2[e * DIM + cc]) * gv;
                    Ye[(size_t)a * DIM + cc] = v;
                }
            }
        }
}

// ---------------- combine two expert outputs per token + final LN ----------------
__global__ __launch_bounds__(256) void combine_lnf_kernel(
    const float* __restrict__ Ye, const float* __restrict__ g, const float* __restrict__ b,
    float* __restrict__ out)
{
    const int t = blockIdx.x, tid = threadIdx.x;
    __shared__ float red[4];
    float2 y0 = reinterpret_cast<const float2*>(Ye + (size_t)(2 * t) * DIM)[tid];
    float2 y1 = reinterpret_cast<const float2*>(Ye + (size_t)(2 * t + 1) * DIM)[tid];
    float z0 = y0.x + y1.x, z1 = y0.y + y1.y;
    float mean = block_sum4(z0 + z1, red, tid) * (1.0f / DIM);
    float d0 = z0 - mean, d1 = z1 - mean;
    float var = block_sum4(d0 * d0 + d1 * d1, red, tid) * (1.0f / DIM);
    float rstd = rsqrtf(var + 1e-5f);
    int d = tid * 2;
    out[(size_t)t * DIM + d]     = d0 * rstd * g[d]     + b[d];
    out[(size_t)t * DIM + d + 1] = d1 * rstd * g[d + 1] + b[d + 1];
    if (t == 0 && tid == 0) out[(size_t)NTOK * DIM] = 0.f;  // aux_loss
}

__global__ void zero_cnt_kernel(int* cnt) {
    if (threadIdx.x < NEXP) cnt[threadIdx.x] = 0;
}

extern "C" void kernel_launch(void* const* d_in, const int* in_sizes, int n_in,
                              void* d_out, int out_size, void* d_ws, size_t ws_size,
                              hipStream_t stream)
{
    (void)in_sizes; (void)n_in; (void)out_size; (void)ws_size;
    const float* x    = (const float*)d_in[0];
    const float* ln1g = (const float*)d_in[1];
    const float* ln1b = (const float*)d_in[2];
    const float* w1   = (const float*)d_in[3];
    const float* b1   = (const float*)d_in[4];
    const float* w2   = (const float*)d_in[5];
    const float* b2   = (const float*)d_in[6];
    const float* ln2g = (const float*)d_in[7];
    const float* ln2b = (const float*)d_in[8];
    const float* wrm  = (const float*)d_in[9];
    const float* ew1  = (const float*)d_in[10];
    const float* eb1  = (const float*)d_in[11];
    const float* ew2  = (const float*)d_in[12];
    const float* eb2  = (const float*)d_in[13];
    const float* lnfg = (const float*)d_in[14];
    const float* lnfb = (const float*)d_in[15];
    float* out = (float*)d_out;

    char* w = (char*)d_ws;
    size_t off = 0;
    auto take = [&](size_t bytes) {
        char* p = w + off;
        off += bytes;
        off = (off + 255) & ~(size_t)255;
        return p;
    };
    half_t* xh_h  = (half_t*)take((size_t)NTOK * DIM * 2);
    half_t* xh_l  = (half_t*)take((size_t)NTOK * DIM * 2);
    half_t* w1t_h = (half_t*)take((size_t)DIM * MHID * 2);
    half_t* w1t_l = (half_t*)take((size_t)DIM * MHID * 2);
    half_t* w2t_h = (half_t*)take((size_t)MHID * DIM * 2);
    half_t* w2t_l = (half_t*)take((size_t)MHID * DIM * 2);
    char*   big   = take((size_t)NTOK * MHID * 2 * 2);        // 64 MiB: a1 hi/lo, later He + Ye
    half_t* a1h   = (half_t*)big;
    half_t* a1l   = (half_t*)(big + (size_t)NTOK * MHID * 2);
    half_t* heh   = (half_t*)big;                              // alias (a1 dead after gemm2)
    float*  yef   = (float*)(big + (size_t)NTOK * MHID * 2);   // alias
    float*  x3f   = (float*)take((size_t)NTOK * DIM * 4);      // h buffer, then x3 f32
    half_t* x3h   = (half_t*)take((size_t)NTOK * DIM * 2);
    half_t* ew1t  = (half_t*)take((size_t)NEXP * DIM * EHID * 2);
    half_t* ew2t  = (half_t*)take((size_t)NEXP * EHID * DIM * 2);
    int*    cnt   = (int*)take(256);
    int*    aid   = (int*)take((size_t)NEXP * NTOK * 4);
    float*  gate  = (float*)take((size_t)NTOK * 2 * 4);

    zero_cnt_kernel<<<1, 64, 0, stream>>>(cnt);
    ln1_split_kernel<<<NTOK, 256, 0, stream>>>(x, ln1g, ln1b, xh_h, xh_l);
    transpose_split_kernel<<<dim3(MHID / 32, DIM / 32, 1), dim3(32, 8), 0, stream>>>(w1, w1t_h, w1t_l, DIM, MHID);
    transpose_split_kernel<<<dim3(DIM / 32, MHID / 32, 1), dim3(32, 8), 0, stream>>>(w2, w2t_h, w2t_l, MHID, DIM);
    transpose_split_kernel<<<dim3(EHID / 32, DIM / 32, NEXP), dim3(32, 8), 0, stream>>>(ew1, ew1t, (half_t*)0, DIM, EHID);
    transpose_split_kernel<<<dim3(DIM / 32, EHID / 32, NEXP), dim3(32, 8), 0, stream>>>(ew2, ew2t, (half_t*)0, EHID, DIM);
    gemm3_kernel<1><<<dim3(NTOK / 128, MHID / 128), 256, 0, stream>>>(
        xh_h, xh_l, w1t_h, w1t_l, b1, (float*)0, a1h, a1l, NTOK, MHID, DIM);
    gemm3_kernel<0><<<dim3(NTOK / 128, DIM / 128), 256, 0, stream>>>(
        a1h, a1l, w2t_h, w2t_l, b2, x3f, (half_t*)0, (half_t*)0, NTOK, DIM, MHID);
    resid_ln2_kernel<<<NTOK, 256, 0, stream>>>(x, x3f, ln2g, ln2b, x3h);
    router_kernel<<<NTOK / 4, 256, 0, stream>>>(x3f, wrm, cnt, aid, gate);
    egemm1_kernel<<<NEXP * (NTOK / 128) * (EHID / 128), 256, 0, stream>>>(x3h, ew1t, eb1, cnt, aid, heh);
    egemm2_kernel<<<NEXP * (NTOK / 128) * (DIM / 128), 256, 0, stream>>>(heh, ew2t, eb2, cnt, aid, gate, yef);
    combine_lnf_kernel<<<NTOK, 256, 0, stream>>>(yef, lnfg, lnfb, out);
}

// Round 5
// 349.293 us; speedup vs baseline: 1.7037x; 1.7037x over previous
//
#include <hip/hip_runtime.h>

#define NTOK 8192
#define DIM  512
#define MHID 2048
#define EHID 1024
#define NEXP 8
#define RBLK 64   // tokens per router block

using half_t = _Float16;
typedef _Float16 f16x8 __attribute__((ext_vector_type(8)));
typedef float    f32x4 __attribute__((ext_vector_type(4)));

__device__ __forceinline__ float gelu_exact(float v) {
    return 0.5f * v * (1.0f + erff(v * 0.70710678118654752f));
}

__device__ __forceinline__ f16x8 f16x8_zero() {
    f16x8 v;
#pragma unroll
    for (int i = 0; i < 8; i++) v[i] = (_Float16)0.f;
    return v;
}

// all-threads-return block sum over 4 waves (256 threads)
__device__ __forceinline__ float block_sum4(float v, float* red, int tid) {
#pragma unroll
    for (int off = 32; off; off >>= 1) v += __shfl_down(v, off);
    if ((tid & 63) == 0) red[tid >> 6] = v;
    __syncthreads();
    float r = red[0] + red[1] + red[2] + red[3];
    __syncthreads();
    return r;
}

// ---------------- LN1 + fp16 hi/lo split ----------------
__global__ __launch_bounds__(256) void ln1_split_kernel(
    const float* __restrict__ x, const float* __restrict__ g, const float* __restrict__ b,
    half_t* __restrict__ xh, half_t* __restrict__ xl)
{
    const int row = blockIdx.x, tid = threadIdx.x;
    __shared__ float red[4];
    const size_t base = (size_t)row * DIM;
    float2 v = reinterpret_cast<const float2*>(x + base)[tid];
    float mean = block_sum4(v.x + v.y, red, tid) * (1.0f / DIM);
    float d0 = v.x - mean, d1 = v.y - mean;
    float var = block_sum4(d0 * d0 + d1 * d1, red, tid) * (1.0f / DIM);
    float rstd = rsqrtf(var + 1e-5f);
    int d = tid * 2;
    float y0 = d0 * rstd * g[d]     + b[d];
    float y1 = d1 * rstd * g[d + 1] + b[d + 1];
    half_t h0 = (half_t)y0, h1 = (half_t)y1;
    xh[base + d] = h0;  xh[base + d + 1] = h1;
    xl[base + d]     = (half_t)(y0 - (float)h0);
    xl[base + d + 1] = (half_t)(y1 - (float)h1);
}

// ---------------- x2 = x + h ; x3 = LN2(x2) + x2 (in place over h) ----------------
__global__ __launch_bounds__(256) void resid_ln2_kernel(
    const float* __restrict__ x, float* __restrict__ hio,
    const float* __restrict__ g, const float* __restrict__ b,
    half_t* __restrict__ x3h)
{
    const int row = blockIdx.x, tid = threadIdx.x;
    __shared__ float red[4];
    const size_t base = (size_t)row * DIM;
    float2 xv = reinterpret_cast<const float2*>(x + base)[tid];
    float2 hv = reinterpret_cast<float2*>(hio + base)[tid];
    float z0 = xv.x + hv.x, z1 = xv.y + hv.y;
    float mean = block_sum4(z0 + z1, red, tid) * (1.0f / DIM);
    float d0 = z0 - mean, d1 = z1 - mean;
    float var = block_sum4(d0 * d0 + d1 * d1, red, tid) * (1.0f / DIM);
    float rstd = rsqrtf(var + 1e-5f);
    int d = tid * 2;
    float y0 = d0 * rstd * g[d]     + b[d]     + z0;
    float y1 = d1 * rstd * g[d + 1] + b[d + 1] + z1;
    float2 o; o.x = y0; o.y = y1;
    reinterpret_cast<float2*>(hio + base)[tid] = o;
    x3h[base + d]     = (half_t)y0;
    x3h[base + d + 1] = (half_t)y1;
}

// ---------------- transpose [R][C] -> [C][R], cast to f16 (optional lo split) ----------------
__global__ void transpose_split_kernel(const float* __restrict__ in,
                                       half_t* __restrict__ oh, half_t* __restrict__ ol,
                                       int R, int C)
{
    __shared__ float t[32][33];
    const size_t mo = (size_t)blockIdx.z * (size_t)R * (size_t)C;
    const int c0 = blockIdx.x * 32, r0 = blockIdx.y * 32;
    const int tx = threadIdx.x, ty = threadIdx.y;
    for (int i = ty; i < 32; i += 8) t[i][tx] = in[mo + (size_t)(r0 + i) * C + c0 + tx];
    __syncthreads();
    for (int i = ty; i < 32; i += 8) {
        float v = t[tx][i];
        size_t o = mo + (size_t)(c0 + i) * R + r0 + tx;
        half_t h = (half_t)v;
        oh[o] = h;
        if (ol) ol[o] = (half_t)(v - (float)h);
    }
}

// ---------------- split-3 f16 MFMA GEMM, merged terms: C = Ah·Bh + Al·Bh + Ah·Bl ----------------
// A: [M][K] f16 hi/lo.  B: [Nc][K] f16 hi/lo (pre-transposed weights).
// EPI==1: gelu(acc+bias) -> split f16 hi/lo outs.  EPI==0: acc+bias -> f32 out.
template <int EPI>
__global__ __launch_bounds__(256) void gemm3_kernel(
    const half_t* __restrict__ A0, const half_t* __restrict__ A1,
    const half_t* __restrict__ B0, const half_t* __restrict__ B1,
    const float* __restrict__ bias,
    float* __restrict__ Cf, half_t* __restrict__ Ch, half_t* __restrict__ Cl,
    int M, int Nc, int K)
{
    __shared__ half_t As[2][128][40];
    __shared__ half_t Bs[2][128][40];
    const int m0 = blockIdx.x * 128, n0 = blockIdx.y * 128;
    const int tid = threadIdx.x;
    const int lane = tid & 63, wid = tid >> 6;
    const int wr = wid >> 1, wc = wid & 1;
    f32x4 acc[4][4];
#pragma unroll
    for (int i = 0; i < 4; i++)
#pragma unroll
        for (int j = 0; j < 4; j++)
#pragma unroll
            for (int q = 0; q < 4; q++) acc[i][j][q] = 0.f;

    const int sm = tid >> 1, sk = (tid & 1) * 16;
    const size_t aoff = (size_t)(m0 + sm) * K + sk;
    const size_t boff = (size_t)(n0 + sm) * K + sk;
    const int kk = (lane >> 4) * 8;
    const int fr = lane & 15;

#pragma unroll 1
    for (int k0 = 0; k0 < K; k0 += 32) {
        __syncthreads();
        *(f16x8*)&As[0][sm][sk]     = *(const f16x8*)(A0 + aoff + k0);
        *(f16x8*)&As[0][sm][sk + 8] = *(const f16x8*)(A0 + aoff + k0 + 8);
        *(f16x8*)&As[1][sm][sk]     = *(const f16x8*)(A1 + aoff + k0);
        *(f16x8*)&As[1][sm][sk + 8] = *(const f16x8*)(A1 + aoff + k0 + 8);
        *(f16x8*)&Bs[0][sm][sk]     = *(const f16x8*)(B0 + boff + k0);
        *(f16x8*)&Bs[0][sm][sk + 8] = *(const f16x8*)(B0 + boff + k0 + 8);
        *(f16x8*)&Bs[1][sm][sk]     = *(const f16x8*)(B1 + boff + k0);
        *(f16x8*)&Bs[1][sm][sk + 8] = *(const f16x8*)(B1 + boff + k0 + 8);
        __syncthreads();
        f16x8 ah[4], al[4], bh[4], bl[4];
#pragma unroll
        for (int i = 0; i < 4; i++) {
            ah[i] = *(const f16x8*)&As[0][wr * 64 + i * 16 + fr][kk];
            al[i] = *(const f16x8*)&As[1][wr * 64 + i * 16 + fr][kk];
            bh[i] = *(const f16x8*)&Bs[0][wc * 64 + i * 16 + fr][kk];
            bl[i] = *(const f16x8*)&Bs[1][wc * 64 + i * 16 + fr][kk];
        }
#pragma unroll
        for (int i = 0; i < 4; i++)
#pragma unroll
            for (int j = 0; j < 4; j++) {
                acc[i][j] = __builtin_amdgcn_mfma_f32_16x16x32_f16(ah[i], bh[j], acc[i][j], 0, 0, 0);
                acc[i][j] = __builtin_amdgcn_mfma_f32_16x16x32_f16(al[i], bh[j], acc[i][j], 0, 0, 0);
                acc[i][j] = __builtin_amdgcn_mfma_f32_16x16x32_f16(ah[i], bl[j], acc[i][j], 0, 0, 0);
            }
    }

    const int rl = (lane >> 4) * 4, cl = lane & 15;
#pragma unroll
    for (int i = 0; i < 4; i++) {
#pragma unroll
        for (int j = 0; j < 4; j++) {
            int cc = n0 + wc * 64 + j * 16 + cl;
            float bv = bias[cc];
#pragma unroll
            for (int q = 0; q < 4; q++) {
                int rr = m0 + wr * 64 + i * 16 + rl + q;
                float v = acc[i][j][q] + bv;
                size_t o = (size_t)rr * Nc + cc;
                if (EPI == 1) {
                    float ge = gelu_exact(v);
                    half_t h = (half_t)ge;
                    Ch[o] = h;
                    Cl[o] = (half_t)(ge - (float)h);
                } else {
                    Cf[o] = v;
                }
            }
        }
    }
}

// ---------------- router: logits, top2, gates, block-aggregated expert lists ----------------
// cnt is PADDED: expert e's counter lives at cnt[e*32] (128 B apart -> 8 cachelines).
__global__ __launch_bounds__(256) void router_kernel(
    const float* __restrict__ x3, const float* __restrict__ wrm,
    int* __restrict__ cnt, int* __restrict__ aid, float* __restrict__ gate)
{
    __shared__ float wl[NEXP][DIM];
    __shared__ int   texp[RBLK * 2];
    __shared__ float tgate[RBLK * 2];
    __shared__ int   lslot[RBLK * 2];
    __shared__ int   lcnt[NEXP], lbase[NEXP];
    const int tid = threadIdx.x;
    for (int i = tid; i < NEXP * DIM / 4; i += 256)
        reinterpret_cast<float4*>(&wl[0][0])[i] = reinterpret_cast<const float4*>(wrm)[i];
    if (tid < NEXP) lcnt[tid] = 0;
    __syncthreads();
    const int w = tid >> 6, lane = tid & 63;
#pragma unroll 1
    for (int t = 0; t < RBLK / 4; ++t) {
        const int lt = w * (RBLK / 4) + t;
        const int token = blockIdx.x * RBLK + lt;
        const float* xr = x3 + (size_t)token * DIM;
        float a[NEXP];
#pragma unroll
        for (int e = 0; e < NEXP; e++) a[e] = 0.f;
#pragma unroll
        for (int d0 = 0; d0 < DIM; d0 += 64) {
            float xv = xr[d0 + lane];
#pragma unroll
            for (int e = 0; e < NEXP; e++) a[e] += xv * wl[e][d0 + lane];
        }
#pragma unroll
        for (int e = 0; e < NEXP; e++)
#pragma unroll
            for (int off = 32; off; off >>= 1) a[e] += __shfl_xor(a[e], off);
        if (lane == 0) {
            // top-2 on logits (softmax is monotonic; ties -> lowest index, as lax.top_k)
            int i1 = 0; float v1 = a[0];
#pragma unroll
            for (int e = 1; e < NEXP; e++) if (a[e] > v1) { v1 = a[e]; i1 = e; }
            int i2 = -1; float v2 = -3.4e38f;
#pragma unroll
            for (int e = 0; e < NEXP; e++) if (e != i1 && a[e] > v2) { v2 = a[e]; i2 = e; }
            // renormalized top-2 gates: softmax denominator cancels
            float e2 = expf(v2 - v1);           // v2 <= v1 -> e2 in (0,1]
            float g1 = 1.0f / (1.0f + e2);
            texp[lt * 2]      = i1; tgate[lt * 2]      = g1;
            texp[lt * 2 + 1]  = i2; tgate[lt * 2 + 1]  = 1.0f - g1;
        }
    }
    __syncthreads();
    if (tid < RBLK * 2) lslot[tid] = atomicAdd(&lcnt[texp[tid]], 1);
    __syncthreads();
    if (tid < NEXP) lbase[tid] = atomicAdd(&cnt[tid * 32], lcnt[tid]);
    __syncthreads();
    if (tid < RBLK * 2) {
        const int e = texp[tid];
        const int asg = blockIdx.x * (RBLK * 2) + tid;   // token*2 + k
        aid[e * NTOK + lbase[e] + lslot[tid]] = asg;
        gate[asg] = tgate[tid];
    }
}

// ---------------- expert GEMM1: He[a] = gelu(x3[tok] @ ew1[e] + eb1[e]) ----------------
__global__ __launch_bounds__(256) void egemm1_kernel(
    const half_t* __restrict__ X,   // [NTOK][DIM]
    const half_t* __restrict__ W,   // [E][EHID][DIM]  (transposed)
    const float* __restrict__ eb1,  // [E][EHID]
    const int* __restrict__ cnt, const int* __restrict__ aid,
    half_t* __restrict__ He)        // [2*NTOK][EHID]
{
    const int bid = blockIdx.x;
    const int e = bid >> 9, rem = bid & 511;
    const int mt = rem >> 3, nt = rem & 7;
    const int ne = cnt[e * 32];
    if (mt * 128 >= ne) return;
    __shared__ half_t As[128][40];
    __shared__ half_t Bs[128][40];
    __shared__ int rowmap[128];
    const int tid = threadIdx.x;
    if (tid < 128) {
        int slot = mt * 128 + tid;
        rowmap[tid] = (slot < ne) ? aid[e * NTOK + slot] : -1;
    }
    __syncthreads();
    const int lane = tid & 63, wid = tid >> 6;
    const int wr = wid >> 1, wc = wid & 1;
    const int sm = tid >> 1, sk = (tid & 1) * 16;
    const int arow = rowmap[sm];
    const half_t* Ap = (arow >= 0) ? X + (size_t)(arow >> 1) * DIM + sk : (const half_t*)0;
    const half_t* Bp = W + (size_t)e * EHID * DIM + (size_t)(nt * 128 + sm) * DIM + sk;
    f32x4 acc[4][4];
#pragma unroll
    for (int i = 0; i < 4; i++)
#pragma unroll
        for (int j = 0; j < 4; j++)
#pragma unroll
            for (int q = 0; q < 4; q++) acc[i][j][q] = 0.f;
    const int kk = (lane >> 4) * 8, fr = lane & 15;
    const f16x8 zz = f16x8_zero();
#pragma unroll 1
    for (int k0 = 0; k0 < DIM; k0 += 32) {
        __syncthreads();
        if (Ap) {
            *(f16x8*)&As[sm][sk]     = *(const f16x8*)(Ap + k0);
            *(f16x8*)&As[sm][sk + 8] = *(const f16x8*)(Ap + k0 + 8);
        } else {
            *(f16x8*)&As[sm][sk]     = zz;
            *(f16x8*)&As[sm][sk + 8] = zz;
        }
        *(f16x8*)&Bs[sm][sk]     = *(const f16x8*)(Bp + k0);
        *(f16x8*)&Bs[sm][sk + 8] = *(const f16x8*)(Bp + k0 + 8);
        __syncthreads();
        f16x8 af[4], bf[4];
#pragma unroll
        for (int i = 0; i < 4; i++) af[i] = *(const f16x8*)&As[wr * 64 + i * 16 + fr][kk];
#pragma unroll
        for (int i = 0; i < 4; i++) bf[i] = *(const f16x8*)&Bs[wc * 64 + i * 16 + fr][kk];
#pragma unroll
        for (int i = 0; i < 4; i++)
#pragma unroll
            for (int j = 0; j < 4; j++)
                acc[i][j] = __builtin_amdgcn_mfma_f32_16x16x32_f16(af[i], bf[j], acc[i][j], 0, 0, 0);
    }
    const int rl = (lane >> 4) * 4, cl = lane & 15;
#pragma unroll
    for (int i = 0; i < 4; i++)
#pragma unroll
        for (int q = 0; q < 4; q++) {
            int r = wr * 64 + i * 16 + rl + q;
            int a = rowmap[r];
            if (a >= 0) {
#pragma unroll
                for (int j = 0; j < 4; j++) {
                    int cc = nt * 128 + wc * 64 + j * 16 + cl;
                    float v = acc[i][j][q] + eb1[e * EHID + cc];
                    He[(size_t)a * EHID + cc] = (half_t)gelu_exact(v);
                }
            }
        }
}

// ---------------- expert GEMM2: Ye[a] = (He[a] @ ew2[e] + eb2[e]) * gate[a] ----------------
__global__ __launch_bounds__(256) void egemm2_kernel(
    const half_t* __restrict__ Hin,  // [2*NTOK][EHID]
    const half_t* __restrict__ W,    // [E][DIM][EHID]  (transposed)
    const float* __restrict__ eb2,   // [E][DIM]
    const int* __restrict__ cnt, const int* __restrict__ aid,
    const float* __restrict__ gate,
    float* __restrict__ Ye)          // [2*NTOK][DIM]
{
    const int bid = blockIdx.x;
    const int e = bid >> 8, rem = bid & 255;
    const int mt = rem >> 2, nt = rem & 3;
    const int ne = cnt[e * 32];
    if (mt * 128 >= ne) return;
    __shared__ half_t As[128][40];
    __shared__ half_t Bs[128][40];
    __shared__ int rowmap[128];
    const int tid = threadIdx.x;
    if (tid < 128) {
        int slot = mt * 128 + tid;
        rowmap[tid] = (slot < ne) ? aid[e * NTOK + slot] : -1;
    }
    __syncthreads();
    const int lane = tid & 63, wid = tid >> 6;
    const int wr = wid >> 1, wc = wid & 1;
    const int sm = tid >> 1, sk = (tid & 1) * 16;
    const int arow = rowmap[sm];
    const half_t* Ap = (arow >= 0) ? Hin + (size_t)arow * EHID + sk : (const half_t*)0;
    const half_t* Bp = W + (size_t)e * DIM * EHID + (size_t)(nt * 128 + sm) * EHID + sk;
    f32x4 acc[4][4];
#pragma unroll
    for (int i = 0; i < 4; i++)
#pragma unroll
        for (int j = 0; j < 4; j++)
#pragma unroll
            for (int q = 0; q < 4; q++) acc[i][j][q] = 0.f;
    const int kk = (lane >> 4) * 8, fr = lane & 15;
    const f16x8 zz = f16x8_zero();
#pragma unroll 1
    for (int k0 = 0; k0 < EHID; k0 += 32) {
        __syncthreads();
        if (Ap) {
            *(f16x8*)&As[sm][sk]     = *(const f16x8*)(Ap + k0);
            *(f16x8*)&As[sm][sk + 8] = *(const f16x8*)(Ap + k0 + 8);
        } else {
            *(f16x8*)&As[sm][sk]     = zz;
            *(f16x8*)&As[sm][sk + 8] = zz;
        }
        *(f16x8*)&Bs[sm][sk]     = *(const f16x8*)(Bp + k0);
        *(f16x8*)&Bs[sm][sk + 8] = *(const f16x8*)(Bp + k0 + 8);
        __syncthreads();
        f16x8 af[4], bf[4];
#pragma unroll
        for (int i = 0; i < 4; i++) af[i] = *(const f16x8*)&As[wr * 64 + i * 16 + fr][kk];
#pragma unroll
        for (int i = 0; i < 4; i++) bf[i] = *(const f16x8*)&Bs[wc * 64 + i * 16 + fr][kk];
#pragma unroll
        for (int i = 0; i < 4; i++)
#pragma unroll
            for (int j = 0; j < 4; j++)
                acc[i][j] = __builtin_amdgcn_mfma_f32_16x16x32_f16(af[i], bf[j], acc[i][j], 0, 0, 0);
    }
    const int rl = (lane >> 4) * 4, cl = lane & 15;
#pragma unroll
    for (int i = 0; i < 4; i++)
#pragma unroll
        for (int q = 0; q < 4; q++) {
            int r = wr * 64 + i * 16 + rl + q;
            int a = rowmap[r];
            if (a >= 0) {
                float gv = gate[a];
#pragma unroll
                for (int j = 0; j < 4; j++) {
                    int cc = nt * 128 + wc * 64 + j * 16 + cl;
                    float v = (acc[i][j][q] + eb2[e * DIM + cc]) * gv;
                    Ye[(size_t)a * DIM + cc] = v;
                }
            }
        }
}

// ---------------- combine two expert outputs per token + final LN ----------------
__global__ __launch_bounds__(256) void combine_lnf_kernel(
    const float* __restrict__ Ye, const float* __restrict__ g, const float* __restrict__ b,
    float* __restrict__ out)
{
    const int t = blockIdx.x, tid = threadIdx.x;
    __shared__ float red[4];
    float2 y0 = reinterpret_cast<const float2*>(Ye + (size_t)(2 * t) * DIM)[tid];
    float2 y1 = reinterpret_cast<const float2*>(Ye + (size_t)(2 * t + 1) * DIM)[tid];
    float z0 = y0.x + y1.x, z1 = y0.y + y1.y;
    float mean = block_sum4(z0 + z1, red, tid) * (1.0f / DIM);
    float d0 = z0 - mean, d1 = z1 - mean;
    float var = block_sum4(d0 * d0 + d1 * d1, red, tid) * (1.0f / DIM);
    float rstd = rsqrtf(var + 1e-5f);
    int d = tid * 2;
    out[(size_t)t * DIM + d]     = d0 * rstd * g[d]     + b[d];
    out[(size_t)t * DIM + d + 1] = d1 * rstd * g[d + 1] + b[d + 1];
    if (t == 0 && tid == 0) out[(size_t)NTOK * DIM] = 0.f;  // aux_loss
}

__global__ void zero_cnt_kernel(int* cnt) {
    cnt[threadIdx.x] = 0;   // zero all 256 padded slots (8 experts * stride 32)
}

extern "C" void kernel_launch(void* const* d_in, const int* in_sizes, int n_in,
                              void* d_out, int out_size, void* d_ws, size_t ws_size,
                              hipStream_t stream)
{
    (void)in_sizes; (void)n_in; (void)out_size; (void)ws_size;
    const float* x    = (const float*)d_in[0];
    const float* ln1g = (const float*)d_in[1];
    const float* ln1b = (const float*)d_in[2];
    const float* w1   = (const float*)d_in[3];
    const float* b1   = (const float*)d_in[4];
    const float* w2   = (const float*)d_in[5];
    const float* b2   = (const float*)d_in[6];
    const float* ln2g = (const float*)d_in[7];
    const float* ln2b = (const float*)d_in[8];
    const float* wrm  = (const float*)d_in[9];
    const float* ew1  = (const float*)d_in[10];
    const float* eb1  = (const float*)d_in[11];
    const float* ew2  = (const float*)d_in[12];
    const float* eb2  = (const float*)d_in[13];
    const float* lnfg = (const float*)d_in[14];
    const float* lnfb = (const float*)d_in[15];
    float* out = (float*)d_out;

    char* w = (char*)d_ws;
    size_t off = 0;
    auto take = [&](size_t bytes) {
        char* p = w + off;
        off += bytes;
        off = (off + 255) & ~(size_t)255;
        return p;
    };
    half_t* xh_h  = (half_t*)take((size_t)NTOK * DIM * 2);
    half_t* xh_l  = (half_t*)take((size_t)NTOK * DIM * 2);
    half_t* w1t_h = (half_t*)take((size_t)DIM * MHID * 2);
    half_t* w1t_l = (half_t*)take((size_t)DIM * MHID * 2);
    half_t* w2t_h = (half_t*)take((size_t)MHID * DIM * 2);
    half_t* w2t_l = (half_t*)take((size_t)MHID * DIM * 2);
    char*   big   = take((size_t)NTOK * MHID * 2 * 2);        // 64 MiB: a1 hi/lo, later He + Ye
    half_t* a1h   = (half_t*)big;
    half_t* a1l   = (half_t*)(big + (size_t)NTOK * MHID * 2);
    half_t* heh   = (half_t*)big;                              // alias (a1 dead after gemm2)
    float*  yef   = (float*)(big + (size_t)NTOK * MHID * 2);   // alias
    float*  x3f   = (float*)take((size_t)NTOK * DIM * 4);      // h buffer, then x3 f32
    half_t* x3h   = (half_t*)take((size_t)NTOK * DIM * 2);
    half_t* ew1t  = (half_t*)take((size_t)NEXP * DIM * EHID * 2);
    half_t* ew2t  = (half_t*)take((size_t)NEXP * EHID * DIM * 2);
    int*    cnt   = (int*)take(1024);                          // 8 experts, 128 B apart
    int*    aid   = (int*)take((size_t)NEXP * NTOK * 4);
    float*  gate  = (float*)take((size_t)NTOK * 2 * 4);

    zero_cnt_kernel<<<1, 256, 0, stream>>>(cnt);
    ln1_split_kernel<<<NTOK, 256, 0, stream>>>(x, ln1g, ln1b, xh_h, xh_l);
    transpose_split_kernel<<<dim3(MHID / 32, DIM / 32, 1), dim3(32, 8), 0, stream>>>(w1, w1t_h, w1t_l, DIM, MHID);
    transpose_split_kernel<<<dim3(DIM / 32, MHID / 32, 1), dim3(32, 8), 0, stream>>>(w2, w2t_h, w2t_l, MHID, DIM);
    transpose_split_kernel<<<dim3(EHID / 32, DIM / 32, NEXP), dim3(32, 8), 0, stream>>>(ew1, ew1t, (half_t*)0, DIM, EHID);
    transpose_split_kernel<<<dim3(DIM / 32, EHID / 32, NEXP), dim3(32, 8), 0, stream>>>(ew2, ew2t, (half_t*)0, EHID, DIM);
    gemm3_kernel<1><<<dim3(NTOK / 128, MHID / 128), 256, 0, stream>>>(
        xh_h, xh_l, w1t_h, w1t_l, b1, (float*)0, a1h, a1l, NTOK, MHID, DIM);
    gemm3_kernel<0><<<dim3(NTOK / 128, DIM / 128), 256, 0, stream>>>(
        a1h, a1l, w2t_h, w2t_l, b2, x3f, (half_t*)0, (half_t*)0, NTOK, DIM, MHID);
    resid_ln2_kernel<<<NTOK, 256, 0, stream>>>(x, x3f, ln2g, ln2b, x3h);
    router_kernel<<<NTOK / RBLK, 256, 0, stream>>>(x3f, wrm, cnt, aid, gate);
    egemm1_kernel<<<NEXP * (NTOK / 128) * (EHID / 128), 256, 0, stream>>>(x3h, ew1t, eb1, cnt, aid, heh);
    egemm2_kernel<<<NEXP * (NTOK / 128) * (DIM / 128), 256, 0, stream>>>(heh, ew2t, eb2, cnt, aid, gate, yef);
    combine_lnf_kernel<<<NTOK, 256, 0, stream>>>(yef, lnfg, lnfb, out);
}

// Round 6
// 324.424 us; speedup vs baseline: 1.8343x; 1.0767x over previous
//
#include <hip/hip_runtime.h>

#define NTOK 8192
#define DIM  512
#define MHID 2048
#define EHID 1024
#define NEXP 8
#define RBLK 64   // tokens per router block

using half_t = _Float16;
typedef _Float16 f16x8 __attribute__((ext_vector_type(8)));
typedef float    f32x16 __attribute__((ext_vector_type(16)));

#define MFMA32(a, b, c) __builtin_amdgcn_mfma_f32_32x32x16_f16((a), (b), (c), 0, 0, 0)

typedef const __attribute__((address_space(1))) void* gas_ptr;
typedef __attribute__((address_space(3))) void*       las_ptr;
__device__ __forceinline__ void gl16(const void* g, void* l) {
    __builtin_amdgcn_global_load_lds((gas_ptr)g, (las_ptr)l, 16, 0, 0);
}

__device__ __forceinline__ float gelu_exact(float v) {
    return 0.5f * v * (1.0f + erff(v * 0.70710678118654752f));
}

// all-threads-return block sum over 4 waves (256 threads)
__device__ __forceinline__ float block_sum4(float v, float* red, int tid) {
#pragma unroll
    for (int off = 32; off; off >>= 1) v += __shfl_down(v, off);
    if ((tid & 63) == 0) red[tid >> 6] = v;
    __syncthreads();
    float r = red[0] + red[1] + red[2] + red[3];
    __syncthreads();
    return r;
}

// ---------------- LN1 + fp16 hi/lo split ----------------
__global__ __launch_bounds__(256) void ln1_split_kernel(
    const float* __restrict__ x, const float* __restrict__ g, const float* __restrict__ b,
    half_t* __restrict__ xh, half_t* __restrict__ xl)
{
    const int row = blockIdx.x, tid = threadIdx.x;
    __shared__ float red[4];
    const size_t base = (size_t)row * DIM;
    float2 v = reinterpret_cast<const float2*>(x + base)[tid];
    float mean = block_sum4(v.x + v.y, red, tid) * (1.0f / DIM);
    float d0 = v.x - mean, d1 = v.y - mean;
    float var = block_sum4(d0 * d0 + d1 * d1, red, tid) * (1.0f / DIM);
    float rstd = rsqrtf(var + 1e-5f);
    int d = tid * 2;
    float y0 = d0 * rstd * g[d]     + b[d];
    float y1 = d1 * rstd * g[d + 1] + b[d + 1];
    half_t h0 = (half_t)y0, h1 = (half_t)y1;
    xh[base + d] = h0;  xh[base + d + 1] = h1;
    xl[base + d]     = (half_t)(y0 - (float)h0);
    xl[base + d + 1] = (half_t)(y1 - (float)h1);
}

// ---- x2 = x + (p0+p1+b2) ; x3 = LN2(x2) + x2 ; write x3 (f32, over p0) + f16 ----
__global__ __launch_bounds__(256) void resid_ln2_kernel(
    const float* __restrict__ x, float* __restrict__ p0, const float* __restrict__ p1,
    const float* __restrict__ b2,
    const float* __restrict__ g, const float* __restrict__ b,
    half_t* __restrict__ x3h)
{
    const int row = blockIdx.x, tid = threadIdx.x;
    __shared__ float red[4];
    const size_t base = (size_t)row * DIM;
    float2 xv = reinterpret_cast<const float2*>(x + base)[tid];
    float2 h0 = reinterpret_cast<float2*>(p0 + base)[tid];
    float2 h1 = reinterpret_cast<const float2*>(p1 + base)[tid];
    float2 bb = reinterpret_cast<const float2*>(b2)[tid];
    float z0 = xv.x + h0.x + h1.x + bb.x, z1 = xv.y + h0.y + h1.y + bb.y;
    float mean = block_sum4(z0 + z1, red, tid) * (1.0f / DIM);
    float d0 = z0 - mean, d1 = z1 - mean;
    float var = block_sum4(d0 * d0 + d1 * d1, red, tid) * (1.0f / DIM);
    float rstd = rsqrtf(var + 1e-5f);
    int d = tid * 2;
    float y0 = d0 * rstd * g[d]     + b[d]     + z0;
    float y1 = d1 * rstd * g[d + 1] + b[d + 1] + z1;
    float2 o; o.x = y0; o.y = y1;
    reinterpret_cast<float2*>(p0 + base)[tid] = o;
    x3h[base + d]     = (half_t)y0;
    x3h[base + d + 1] = (half_t)y1;
}

// ---------------- transpose [R][C] -> [C][R], cast to f16 (optional lo split) ----------------
__global__ void transpose_split_kernel(const float* __restrict__ in,
                                       half_t* __restrict__ oh, half_t* __restrict__ ol,
                                       int R, int C)
{
    __shared__ float t[32][33];
    const size_t mo = (size_t)blockIdx.z * (size_t)R * (size_t)C;
    const int c0 = blockIdx.x * 32, r0 = blockIdx.y * 32;
    const int tx = threadIdx.x, ty = threadIdx.y;
    for (int i = ty; i < 32; i += 8) t[i][tx] = in[mo + (size_t)(r0 + i) * C + c0 + tx];
    __syncthreads();
    for (int i = ty; i < 32; i += 8) {
        float v = t[tx][i];
        size_t o = mo + (size_t)(c0 + i) * R + r0 + tx;
        half_t h = (half_t)v;
        oh[o] = h;
        if (ol) ol[o] = (half_t)(v - (float)h);
    }
}

// ======== split-3 f16 MFMA GEMM, 32x32x16, global_load_lds + slot-XOR swizzle ========
// A: [M][K] f16 hi/lo.  B: [Nc][K] f16 hi/lo.  128x128 tile, 4 waves (2x2), BK=32.
// LDS tiles are [128 rows][4 slots of 16B], slot position = slot ^ ((row>>1)&3).
// EPI==1: gelu(acc+bias) -> split f16 hi/lo.  EPI==0: raw acc -> f32 (split-K partial,
// buffer selected by blockIdx.z; kbeg = z*Ktile).
template <int EPI>
__global__ __launch_bounds__(256) void gemm3_kernel(
    const half_t* __restrict__ A0, const half_t* __restrict__ A1,
    const half_t* __restrict__ B0, const half_t* __restrict__ B1,
    const float* __restrict__ bias,
    float* __restrict__ Cf0, float* __restrict__ Cf1,
    half_t* __restrict__ Ch, half_t* __restrict__ Cl,
    int Nc, int K, int Ktile)
{
    __shared__ __align__(16) half_t As0[128 * 32];
    __shared__ __align__(16) half_t As1[128 * 32];
    __shared__ __align__(16) half_t Bs0[128 * 32];
    __shared__ __align__(16) half_t Bs1[128 * 32];
    const int m0 = blockIdx.x * 128, n0 = blockIdx.y * 128;
    const int kbeg = blockIdx.z * Ktile;
    float* Cf = blockIdx.z ? Cf1 : Cf0;
    const int tid = threadIdx.x;
    const int lane = tid & 63, wid = tid >> 6;
    const int wr = wid >> 1, wc = wid & 1;

    // staging: 512 chunks of 16B per tile; thread stages chunks tid and tid+256.
    const int c0 = tid, c1 = tid + 256;
    const int r0 = c0 >> 2, s0 = (c0 & 3) ^ ((r0 >> 1) & 3);
    const int r1 = c1 >> 2, s1 = (c1 & 3) ^ ((r1 >> 1) & 3);
    const size_t aoff0 = (size_t)(m0 + r0) * K + kbeg + s0 * 8;
    const size_t aoff1 = (size_t)(m0 + r1) * K + kbeg + s1 * 8;
    const size_t boff0 = (size_t)(n0 + r0) * K + kbeg + s0 * 8;
    const size_t boff1 = (size_t)(n0 + r1) * K + kbeg + s1 * 8;

    // fragment LDS offsets (loop-invariant): row = rbase + (lane&31), slot = (lane>>5)+2*kh
    const int l31 = lane & 31, l5 = lane >> 5;
    int oa[2][2], ob[2][2];
#pragma unroll
    for (int i = 0; i < 2; i++)
#pragma unroll
        for (int kh = 0; kh < 2; kh++) {
            int ra = wr * 64 + i * 32 + l31;
            oa[i][kh] = ra * 32 + (((l5 + kh * 2) ^ ((ra >> 1) & 3)) << 3);
            int rb = wc * 64 + i * 32 + l31;
            ob[i][kh] = rb * 32 + (((l5 + kh * 2) ^ ((rb >> 1) & 3)) << 3);
        }

    f32x16 acc[2][2];
#pragma unroll
    for (int i = 0; i < 2; i++)
#pragma unroll
        for (int j = 0; j < 2; j++)
#pragma unroll
            for (int q = 0; q < 16; q++) acc[i][j][q] = 0.f;

#pragma unroll 1
    for (int k0 = 0; k0 < Ktile; k0 += 32) {
        __syncthreads();
        gl16(A0 + aoff0 + k0, As0 + c0 * 8);
        gl16(A0 + aoff1 + k0, As0 + c1 * 8);
        gl16(A1 + aoff0 + k0, As1 + c0 * 8);
        gl16(A1 + aoff1 + k0, As1 + c1 * 8);
        gl16(B0 + boff0 + k0, Bs0 + c0 * 8);
        gl16(B0 + boff1 + k0, Bs0 + c1 * 8);
        gl16(B1 + boff0 + k0, Bs1 + c0 * 8);
        gl16(B1 + boff1 + k0, Bs1 + c1 * 8);
        __syncthreads();
#pragma unroll
        for (int kh = 0; kh < 2; kh++) {
            f16x8 ah0 = *(const f16x8*)(As0 + oa[0][kh]);
            f16x8 ah1 = *(const f16x8*)(As0 + oa[1][kh]);
            f16x8 al0 = *(const f16x8*)(As1 + oa[0][kh]);
            f16x8 al1 = *(const f16x8*)(As1 + oa[1][kh]);
            f16x8 bh0 = *(const f16x8*)(Bs0 + ob[0][kh]);
            f16x8 bh1 = *(const f16x8*)(Bs0 + ob[1][kh]);
            f16x8 bl0 = *(const f16x8*)(Bs1 + ob[0][kh]);
            f16x8 bl1 = *(const f16x8*)(Bs1 + ob[1][kh]);
            acc[0][0] = MFMA32(ah0, bh0, acc[0][0]);
            acc[0][0] = MFMA32(al0, bh0, acc[0][0]);
            acc[0][0] = MFMA32(ah0, bl0, acc[0][0]);
            acc[0][1] = MFMA32(ah0, bh1, acc[0][1]);
            acc[0][1] = MFMA32(al0, bh1, acc[0][1]);
            acc[0][1] = MFMA32(ah0, bl1, acc[0][1]);
            acc[1][0] = MFMA32(ah1, bh0, acc[1][0]);
            acc[1][0] = MFMA32(al1, bh0, acc[1][0]);
            acc[1][0] = MFMA32(ah1, bl0, acc[1][0]);
            acc[1][1] = MFMA32(ah1, bh1, acc[1][1]);
            acc[1][1] = MFMA32(al1, bh1, acc[1][1]);
            acc[1][1] = MFMA32(ah1, bl1, acc[1][1]);
        }
    }

    // C/D 32x32 layout: col = lane&31, row = 4*(lane>>5) + 8*(reg>>2) + (reg&3)
    const int er = 4 * l5;
#pragma unroll
    for (int i = 0; i < 2; i++)
#pragma unroll
        for (int j = 0; j < 2; j++) {
            int cc = n0 + wc * 64 + j * 32 + l31;
            float bv = (EPI == 1) ? bias[cc] : 0.f;
#pragma unroll
            for (int reg = 0; reg < 16; reg++) {
                int rr = m0 + wr * 64 + i * 32 + er + 8 * (reg >> 2) + (reg & 3);
                float v = acc[i][j][reg] + bv;
                size_t o = (size_t)rr * Nc + cc;
                if (EPI == 1) {
                    float ge = gelu_exact(v);
                    half_t h = (half_t)ge;
                    Ch[o] = h;
                    Cl[o] = (half_t)(ge - (float)h);
                } else {
                    Cf[o] = v;
                }
            }
        }
}

// ---------------- router: logits, top2, gates, block-aggregated expert lists ----------------
// cnt is PADDED: expert e's counter lives at cnt[e*32] (128 B apart -> 8 cachelines).
__global__ __launch_bounds__(256) void router_kernel(
    const float* __restrict__ x3, const float* __restrict__ wrm,
    int* __restrict__ cnt, int* __restrict__ aid, float* __restrict__ gate)
{
    __shared__ float wl[NEXP][DIM];
    __shared__ int   texp[RBLK * 2];
    __shared__ float tgate[RBLK * 2];
    __shared__ int   lslot[RBLK * 2];
    __shared__ int   lcnt[NEXP], lbase[NEXP];
    const int tid = threadIdx.x;
    for (int i = tid; i < NEXP * DIM / 4; i += 256)
        reinterpret_cast<float4*>(&wl[0][0])[i] = reinterpret_cast<const float4*>(wrm)[i];
    if (tid < NEXP) lcnt[tid] = 0;
    __syncthreads();
    const int w = tid >> 6, lane = tid & 63;
#pragma unroll 1
    for (int t = 0; t < RBLK / 4; ++t) {
        const int lt = w * (RBLK / 4) + t;
        const int token = blockIdx.x * RBLK + lt;
        const float* xr = x3 + (size_t)token * DIM;
        float a[NEXP];
#pragma unroll
        for (int e = 0; e < NEXP; e++) a[e] = 0.f;
#pragma unroll
        for (int d0 = 0; d0 < DIM; d0 += 64) {
            float xv = xr[d0 + lane];
#pragma unroll
            for (int e = 0; e < NEXP; e++) a[e] += xv * wl[e][d0 + lane];
        }
#pragma unroll
        for (int e = 0; e < NEXP; e++)
#pragma unroll
            for (int off = 32; off; off >>= 1) a[e] += __shfl_xor(a[e], off);
        if (lane == 0) {
            int i1 = 0; float v1 = a[0];
#pragma unroll
            for (int e = 1; e < NEXP; e++) if (a[e] > v1) { v1 = a[e]; i1 = e; }
            int i2 = -1; float v2 = -3.4e38f;
#pragma unroll
            for (int e = 0; e < NEXP; e++) if (e != i1 && a[e] > v2) { v2 = a[e]; i2 = e; }
            float e2 = expf(v2 - v1);
            float g1 = 1.0f / (1.0f + e2);
            texp[lt * 2]      = i1; tgate[lt * 2]      = g1;
            texp[lt * 2 + 1]  = i2; tgate[lt * 2 + 1]  = 1.0f - g1;
        }
    }
    __syncthreads();
    if (tid < RBLK * 2) lslot[tid] = atomicAdd(&lcnt[texp[tid]], 1);
    __syncthreads();
    if (tid < NEXP) lbase[tid] = atomicAdd(&cnt[tid * 32], lcnt[tid]);
    __syncthreads();
    if (tid < RBLK * 2) {
        const int e = texp[tid];
        const int asg = blockIdx.x * (RBLK * 2) + tid;   // token*2 + k
        aid[e * NTOK + lbase[e] + lslot[tid]] = asg;
        gate[asg] = tgate[tid];
    }
}

// ---------------- expert GEMM1: He[a] = gelu(x3[tok] @ ew1[e] + eb1[e]) ----------------
__global__ __launch_bounds__(256) void egemm1_kernel(
    const half_t* __restrict__ X,   // [NTOK][DIM]
    const half_t* __restrict__ W,   // [E][EHID][DIM]
    const float* __restrict__ eb1,
    const int* __restrict__ cnt, const int* __restrict__ aid,
    half_t* __restrict__ He)        // [2*NTOK][EHID]
{
    const int bid = blockIdx.x;
    const int e = bid >> 9, rem = bid & 511;
    const int mt = rem >> 3, nt = rem & 7;
    const int ne = cnt[e * 32];
    if (mt * 128 >= ne) return;
    __shared__ __align__(16) half_t As[128 * 32];
    __shared__ __align__(16) half_t Bs[128 * 32];
    __shared__ int rowmap[128];
    const int tid = threadIdx.x;
    if (tid < 128) {
        int slot = mt * 128 + tid;
        rowmap[tid] = (slot < ne) ? aid[e * NTOK + slot] : -1;
    }
    __syncthreads();
    const int lane = tid & 63, wid = tid >> 6;
    const int wr = wid >> 1, wc = wid & 1;
    const int c0 = tid, c1 = tid + 256;
    const int r0 = c0 >> 2, s0 = (c0 & 3) ^ ((r0 >> 1) & 3);
    const int r1 = c1 >> 2, s1 = (c1 & 3) ^ ((r1 >> 1) & 3);
    const int a0r = rowmap[r0], a1r = rowmap[r1];
    const half_t* pa0 = X + (size_t)(a0r >= 0 ? (a0r >> 1) : 0) * DIM + s0 * 8;
    const half_t* pa1 = X + (size_t)(a1r >= 0 ? (a1r >> 1) : 0) * DIM + s1 * 8;
    const half_t* pb0 = W + (size_t)e * EHID * DIM + (size_t)(nt * 128 + r0) * DIM + s0 * 8;
    const half_t* pb1 = W + (size_t)e * EHID * DIM + (size_t)(nt * 128 + r1) * DIM + s1 * 8;

    const int l31 = lane & 31, l5 = lane >> 5;
    int oa[2][2], ob[2][2];
#pragma unroll
    for (int i = 0; i < 2; i++)
#pragma unroll
        for (int kh = 0; kh < 2; kh++) {
            int ra = wr * 64 + i * 32 + l31;
            oa[i][kh] = ra * 32 + (((l5 + kh * 2) ^ ((ra >> 1) & 3)) << 3);
            int rb = wc * 64 + i * 32 + l31;
            ob[i][kh] = rb * 32 + (((l5 + kh * 2) ^ ((rb >> 1) & 3)) << 3);
        }
    f32x16 acc[2][2];
#pragma unroll
    for (int i = 0; i < 2; i++)
#pragma unroll
        for (int j = 0; j < 2; j++)
#pragma unroll
            for (int q = 0; q < 16; q++) acc[i][j][q] = 0.f;

#pragma unroll 1
    for (int k0 = 0; k0 < DIM; k0 += 32) {
        __syncthreads();
        gl16(pa0 + k0, As + c0 * 8);
        gl16(pa1 + k0, As + c1 * 8);
        gl16(pb0 + k0, Bs + c0 * 8);
        gl16(pb1 + k0, Bs + c1 * 8);
        __syncthreads();
#pragma unroll
        for (int kh = 0; kh < 2; kh++) {
            f16x8 a0 = *(const f16x8*)(As + oa[0][kh]);
            f16x8 a1 = *(const f16x8*)(As + oa[1][kh]);
            f16x8 b0 = *(const f16x8*)(Bs + ob[0][kh]);
            f16x8 b1 = *(const f16x8*)(Bs + ob[1][kh]);
            acc[0][0] = MFMA32(a0, b0, acc[0][0]);
            acc[0][1] = MFMA32(a0, b1, acc[0][1]);
            acc[1][0] = MFMA32(a1, b0, acc[1][0]);
            acc[1][1] = MFMA32(a1, b1, acc[1][1]);
        }
    }
    const int er = 4 * l5;
#pragma unroll
    for (int i = 0; i < 2; i++)
#pragma unroll
        for (int reg = 0; reg < 16; reg++) {
            int rloc = wr * 64 + i * 32 + er + 8 * (reg >> 2) + (reg & 3);
            int a = rowmap[rloc];
            if (a >= 0) {
#pragma unroll
                for (int j = 0; j < 2; j++) {
                    int cc = nt * 128 + wc * 64 + j * 32 + l31;
                    float v = acc[i][j][reg] + eb1[e * EHID + cc];
                    He[(size_t)a * EHID + cc] = (half_t)gelu_exact(v);
                }
            }
        }
}

// ---------------- expert GEMM2: Ye[a] = (He[a] @ ew2[e] + eb2[e]) * gate[a] ----------------
__global__ __launch_bounds__(256) void egemm2_kernel(
    const half_t* __restrict__ Hin,  // [2*NTOK][EHID]
    const half_t* __restrict__ W,    // [E][DIM][EHID]
    const float* __restrict__ eb2,
    const int* __restrict__ cnt, const int* __restrict__ aid,
    const float* __restrict__ gate,
    float* __restrict__ Ye)          // [2*NTOK][DIM]
{
    const int bid = blockIdx.x;
    const int e = bid >> 8, rem = bid & 255;
    const int mt = rem >> 2, nt = rem & 3;
    const int ne = cnt[e * 32];
    if (mt * 128 >= ne) return;
    __shared__ __align__(16) half_t As[128 * 32];
    __shared__ __align__(16) half_t Bs[128 * 32];
    __shared__ int rowmap[128];
    const int tid = threadIdx.x;
    if (tid < 128) {
        int slot = mt * 128 + tid;
        rowmap[tid] = (slot < ne) ? aid[e * NTOK + slot] : -1;
    }
    __syncthreads();
    const int lane = tid & 63, wid = tid >> 6;
    const int wr = wid >> 1, wc = wid & 1;
    const int c0 = tid, c1 = tid + 256;
    const int r0 = c0 >> 2, s0 = (c0 & 3) ^ ((r0 >> 1) & 3);
    const int r1 = c1 >> 2, s1 = (c1 & 3) ^ ((r1 >> 1) & 3);
    const int a0r = rowmap[r0], a1r = rowmap[r1];
    const half_t* pa0 = Hin + (size_t)(a0r >= 0 ? a0r : 0) * EHID + s0 * 8;
    const half_t* pa1 = Hin + (size_t)(a1r >= 0 ? a1r : 0) * EHID + s1 * 8;
    const half_t* pb0 = W + (size_t)e * DIM * EHID + (size_t)(nt * 128 + r0) * EHID + s0 * 8;
    const half_t* pb1 = W + (size_t)e * DIM * EHID + (size_t)(nt * 128 + r1) * EHID + s1 * 8;

    const int l31 = lane & 31, l5 = lane >> 5;
    int oa[2][2], ob[2][2];
#pragma unroll
    for (int i = 0; i < 2; i++)
#pragma unroll
        for (int kh = 0; kh < 2; kh++) {
            int ra = wr * 64 + i * 32 + l31;
            oa[i][kh] = ra * 32 + (((l5 + kh * 2) ^ ((ra >> 1) & 3)) << 3);
            int rb = wc * 64 + i * 32 + l31;
            ob[i][kh] = rb * 32 + (((l5 + kh * 2) ^ ((rb >> 1) & 3)) << 3);
        }
    f32x16 acc[2][2];
#pragma unroll
    for (int i = 0; i < 2; i++)
#pragma unroll
        for (int j = 0; j < 2; j++)
#pragma unroll
            for (int q = 0; q < 16; q++) acc[i][j][q] = 0.f;

#pragma unroll 1
    for (int k0 = 0; k0 < EHID; k0 += 32) {
        __syncthreads();
        gl16(pa0 + k0, As + c0 * 8);
        gl16(pa1 + k0, As + c1 * 8);
        gl16(pb0 + k0, Bs + c0 * 8);
        gl16(pb1 + k0, Bs + c1 * 8);
        __syncthreads();
#pragma unroll
        for (int kh = 0; kh < 2; kh++) {
            f16x8 a0 = *(const f16x8*)(As + oa[0][kh]);
            f16x8 a1 = *(const f16x8*)(As + oa[1][kh]);
            f16x8 b0 = *(const f16x8*)(Bs + ob[0][kh]);
            f16x8 b1 = *(const f16x8*)(Bs + ob[1][kh]);
            acc[0][0] = MFMA32(a0, b0, acc[0][0]);
            acc[0][1] = MFMA32(a0, b1, acc[0][1]);
            acc[1][0] = MFMA32(a1, b0, acc[1][0]);
            acc[1][1] = MFMA32(a1, b1, acc[1][1]);
        }
    }
    const int er = 4 * l5;
#pragma unroll
    for (int i = 0; i < 2; i++)
#pragma unroll
        for (int reg = 0; reg < 16; reg++) {
            int rloc = wr * 64 + i * 32 + er + 8 * (reg >> 2) + (reg & 3);
            int a = rowmap[rloc];
            if (a >= 0) {
                float gv = gate[a];
#pragma unroll
                for (int j = 0; j < 2; j++) {
                    int cc = nt * 128 + wc * 64 + j * 32 + l31;
                    float v = (acc[i][j][reg] + eb2[e * DIM + cc]) * gv;
                    Ye[(size_t)a * DIM + cc] = v;
                }
            }
        }
}

// ---------------- combine two expert outputs per token + final LN ----------------
__global__ __launch_bounds__(256) void combine_lnf_kernel(
    const float* __restrict__ Ye, const float* __restrict__ g, const float* __restrict__ b,
    float* __restrict__ out)
{
    const int t = blockIdx.x, tid = threadIdx.x;
    __shared__ float red[4];
    float2 y0 = reinterpret_cast<const float2*>(Ye + (size_t)(2 * t) * DIM)[tid];
    float2 y1 = reinterpret_cast<const float2*>(Ye + (size_t)(2 * t + 1) * DIM)[tid];
    float z0 = y0.x + y1.x, z1 = y0.y + y1.y;
    float mean = block_sum4(z0 + z1, red, tid) * (1.0f / DIM);
    float d0 = z0 - mean, d1 = z1 - mean;
    float var = block_sum4(d0 * d0 + d1 * d1, red, tid) * (1.0f / DIM);
    float rstd = rsqrtf(var + 1e-5f);
    int d = tid * 2;
    out[(size_t)t * DIM + d]     = d0 * rstd * g[d]     + b[d];
    out[(size_t)t * DIM + d + 1] = d1 * rstd * g[d + 1] + b[d + 1];
    if (t == 0 && tid == 0) out[(size_t)NTOK * DIM] = 0.f;  // aux_loss
}

__global__ void zero_cnt_kernel(int* cnt) {
    cnt[threadIdx.x] = 0;   // zero all 256 padded slots (8 experts * stride 32)
}

extern "C" void kernel_launch(void* const* d_in, const int* in_sizes, int n_in,
                              void* d_out, int out_size, void* d_ws, size_t ws_size,
                              hipStream_t stream)
{
    (void)in_sizes; (void)n_in; (void)out_size; (void)ws_size;
    const float* x    = (const float*)d_in[0];
    const float* ln1g = (const float*)d_in[1];
    const float* ln1b = (const float*)d_in[2];
    const float* w1   = (const float*)d_in[3];
    const float* b1   = (const float*)d_in[4];
    const float* w2   = (const float*)d_in[5];
    const float* b2   = (const float*)d_in[6];
    const float* ln2g = (const float*)d_in[7];
    const float* ln2b = (const float*)d_in[8];
    const float* wrm  = (const float*)d_in[9];
    const float* ew1  = (const float*)d_in[10];
    const float* eb1  = (const float*)d_in[11];
    const float* ew2  = (const float*)d_in[12];
    const float* eb2  = (const float*)d_in[13];
    const float* lnfg = (const float*)d_in[14];
    const float* lnfb = (const float*)d_in[15];
    float* out = (float*)d_out;

    char* w = (char*)d_ws;
    size_t off = 0;
    auto take = [&](size_t bytes) {
        char* p = w + off;
        off += bytes;
        off = (off + 255) & ~(size_t)255;
        return p;
    };
    half_t* xh_h  = (half_t*)take((size_t)NTOK * DIM * 2);   // also split-K partial p1 (f32, 16MB)
    half_t* xh_l  = (half_t*)take((size_t)NTOK * DIM * 2);
    half_t* w1t_h = (half_t*)take((size_t)DIM * MHID * 2);
    half_t* w1t_l = (half_t*)take((size_t)DIM * MHID * 2);
    half_t* w2t_h = (half_t*)take((size_t)MHID * DIM * 2);
    half_t* w2t_l = (half_t*)take((size_t)MHID * DIM * 2);
    char*   big   = take((size_t)NTOK * MHID * 2 * 2);        // 64 MiB: a1 hi/lo, later He + Ye
    half_t* a1h   = (half_t*)big;
    half_t* a1l   = (half_t*)(big + (size_t)NTOK * MHID * 2);
    half_t* heh   = (half_t*)big;                              // alias (a1 dead after gemm3<0>)
    float*  yef   = (float*)(big + (size_t)NTOK * MHID * 2);   // alias
    float*  x3f   = (float*)take((size_t)NTOK * DIM * 4);      // split-K partial p0, then x3 f32
    half_t* x3h   = (half_t*)take((size_t)NTOK * DIM * 2);
    half_t* ew1t  = (half_t*)take((size_t)NEXP * DIM * EHID * 2);
    half_t* ew2t  = (half_t*)take((size_t)NEXP * EHID * DIM * 2);
    int*    cnt   = (int*)take(1024);                          // 8 experts, 128 B apart
    int*    aid   = (int*)take((size_t)NEXP * NTOK * 4);
    float*  gate  = (float*)take((size_t)NTOK * 2 * 4);

    float* p0 = x3f;
    float* p1 = (float*)xh_h;   // xh_h+xh_l = contiguous 16 MB, dead after gemm3<1>

    zero_cnt_kernel<<<1, 256, 0, stream>>>(cnt);
    ln1_split_kernel<<<NTOK, 256, 0, stream>>>(x, ln1g, ln1b, xh_h, xh_l);
    transpose_split_kernel<<<dim3(MHID / 32, DIM / 32, 1), dim3(32, 8), 0, stream>>>(w1, w1t_h, w1t_l, DIM, MHID);
    transpose_split_kernel<<<dim3(DIM / 32, MHID / 32, 1), dim3(32, 8), 0, stream>>>(w2, w2t_h, w2t_l, MHID, DIM);
    transpose_split_kernel<<<dim3(EHID / 32, DIM / 32, NEXP), dim3(32, 8), 0, stream>>>(ew1, ew1t, (half_t*)0, DIM, EHID);
    transpose_split_kernel<<<dim3(DIM / 32, EHID / 32, NEXP), dim3(32, 8), 0, stream>>>(ew2, ew2t, (half_t*)0, EHID, DIM);
    // MLP GEMM1: [8192x512] @ [512x2048], gelu, split out
    gemm3_kernel<1><<<dim3(NTOK / 128, MHID / 128, 1), 256, 0, stream>>>(
        xh_h, xh_l, w1t_h, w1t_l, b1, (float*)0, (float*)0, a1h, a1l, MHID, DIM, DIM);
    // MLP GEMM2: [8192x2048] @ [2048x512], split-K=2 raw partials (bias fused in resid_ln2)
    gemm3_kernel<0><<<dim3(NTOK / 128, DIM / 128, 2), 256, 0, stream>>>(
        a1h, a1l, w2t_h, w2t_l, (const float*)0, p0, p1, (half_t*)0, (half_t*)0, DIM, MHID, MHID / 2);
    resid_ln2_kernel<<<NTOK, 256, 0, stream>>>(x, p0, p1, b2, ln2g, ln2b, x3h);
    router_kernel<<<NTOK / RBLK, 256, 0, stream>>>(x3f, wrm, cnt, aid, gate);
    egemm1_kernel<<<NEXP * (NTOK / 128) * (EHID / 128), 256, 0, stream>>>(x3h, ew1t, eb1, cnt, aid, heh);
    egemm2_kernel<<<NEXP * (NTOK / 128) * (DIM / 128), 256, 0, stream>>>(heh, ew2t, eb2, cnt, aid, gate, yef);
    combine_lnf_kernel<<<NTOK, 256, 0, stream>>>(yef, lnfg, lnfb, out);
}